// Round 2
// baseline (908.479 us; speedup 1.0000x reference)
//
#include <hip/hip_runtime.h>
#include <math.h>

// Problem constants
#define BB_ 128      // batch
#define TT_ 128      // seq len
#define HDIM 768
#define ED 300       // ENCODER_DIM
#define NI 60        // NUM_INTENTS
#define NS 100       // NUM_SLOTS
#define NTOK 16256   // B*(T-1)
#define MTOT 32868   // 2*B*T + NS rows through the encoder GEMM

// ---- workspace layout (float offsets); requires ~55.2 MB of d_ws ----
#define WS_ENC1  0          // (B*T, 300)
#define WS_ENC2  4915200    // (B*T, 300)
#define WS_SPE   9830400    // (100, 300) slot_proto_enc
#define WS_ISUM  9860400    // (60,300)
#define WS_ICNT  9878400    // (60)
#define WS_NPTI  9878464    // (300,60)  normalized intent protos, transposed
#define WS_NPTS  9896464    // (300,100) normalized slot protos, transposed
#define WS_SSUM  9926464    // (100,300)
#define WS_SCNT  9956464    // (100)
#define WS_PART  9956608    // 254 * 15050 partial slot segment sums
#define WS_LOSSI 13779328   // (128)
#define WS_LOSSS 13779456   // (16256)

// ---- output layout (float offsets into d_out) ----
#define O_ILOG   0          // (128,1,60)
#define O_SLOG   7680       // (128,127,1,100)
#define O_ILOSS  1633280
#define O_SLOSS  1633281
#define O_TLOSS  1633282
#define O_IPROTO 1633283    // (60,300)
#define O_ICNT   1651283    // (60)
#define O_SPROTO 1651343    // (100,300)
#define O_SCNT   1681343    // (100)

// ============================================================
// K1: encoder GEMM. C[m,n] = sum_k X[m,k]*W[n,k] + b[n]
// M = 32868 virtual rows (lm1 | lm2 | slot_proto_in), N=300, K=768.
// BM=64 rows/block, full N=300 per block (A read exactly once from HBM).
// 320 threads = 16 row-groups x 20 col-groups; micro-tile 4x16.
// ============================================================
__global__ __launch_bounds__(320) void gemm_enc(
    const float* __restrict__ lm1, const float* __restrict__ lm2,
    const float* __restrict__ spin, const float* __restrict__ W,
    const float* __restrict__ bias, float* __restrict__ ws) {
  __shared__ float As[16][68];    // [k][row], padded
  __shared__ float Bs[16][400];   // [k][colgroup*20 + colingroup], skewed to spread banks
  int mt = blockIdx.x;
  int m0 = mt * 64;
  const float* src; int srow, mrows;
  if (mt < 256)      { src = lm1;  srow = m0;         mrows = 64; }
  else if (mt < 512) { src = lm2;  srow = m0 - 16384; mrows = 64; }
  else               { src = spin; srow = m0 - 32768; mrows = 100 - srow; }
  int tid = threadIdx.x;
  int ty = tid / 20;    // row group 0..15
  int tx = tid % 20;    // col group 0..19 (16 cols each, 320 cols incl pad)
  float acc[4][16] = {};
  int alr = tid >> 2;           // A loader row 0..79 (only <64 used)
  int alk = (tid & 3) * 4;      // A loader k base
  bool aload = alr < 64;
  bool aval = aload && (alr < mrows);
  const float* aptr = src + (size_t)(srow + alr) * HDIM + alk;

  for (int k0 = 0; k0 < HDIM; k0 += 16) {
    if (aload) {
      float4 av = aval ? *(const float4*)(aptr + k0) : make_float4(0.f,0.f,0.f,0.f);
      As[alk+0][alr] = av.x; As[alk+1][alr] = av.y;
      As[alk+2][alr] = av.z; As[alk+3][alr] = av.w;
    }
    // B tile: W rows (=output cols) 0..319, k0..k0+15
    for (int idx = tid; idx < 1280; idx += 320) {
      int n = idx >> 2;              // 0..319
      int kb = (idx & 3) * 4;
      float4 bv = (n < 300) ? *(const float4*)(W + (size_t)n * HDIM + k0 + kb)
                            : make_float4(0.f,0.f,0.f,0.f);
      int c = (n >> 4) * 20 + (n & 15);
      Bs[kb+0][c] = bv.x; Bs[kb+1][c] = bv.y; Bs[kb+2][c] = bv.z; Bs[kb+3][c] = bv.w;
    }
    __syncthreads();
    #pragma unroll
    for (int kk = 0; kk < 16; kk++) {
      float afrag[4];
      *(float4*)afrag = *(const float4*)&As[kk][ty * 4];
      float bfrag[16];
      #pragma unroll
      for (int j4 = 0; j4 < 4; j4++)
        *(float4*)&bfrag[j4 * 4] = *(const float4*)&Bs[kk][tx * 20 + j4 * 4];
      #pragma unroll
      for (int i = 0; i < 4; i++)
        #pragma unroll
        for (int j = 0; j < 16; j++)
          acc[i][j] = fmaf(afrag[i], bfrag[j], acc[i][j]);
    }
    __syncthreads();
  }
  #pragma unroll
  for (int i = 0; i < 4; i++) {
    int r = ty * 4 + i;
    if (r >= mrows) continue;
    size_t m = (size_t)m0 + r;
    #pragma unroll
    for (int j = 0; j < 16; j++) {
      int n = tx * 16 + j;
      if (n < 300) ws[m * ED + n] = acc[i][j] + bias[n];
    }
  }
}

// ============================================================
// K2: intent segment sums (deterministic, b-ascending like segment_sum)
// ============================================================
__global__ __launch_bounds__(320) void intent_seg(
    const float* __restrict__ enc1, const int* __restrict__ il1,
    float* __restrict__ isum, float* __restrict__ icnt) {
  int seg = blockIdx.x, tid = threadIdx.x;
  if (tid < ED) {
    float a = 0.f;
    for (int b = 0; b < BB_; b++)
      if (il1[b] == seg) a += enc1[(size_t)(b * TT_) * ED + tid];
    isum[seg * ED + tid] = a;
  } else if (tid == ED) {
    float c = 0.f;
    for (int b = 0; b < BB_; b++) c += (il1[b] == seg) ? 1.f : 0.f;
    icnt[seg] = c;
  }
}

// ============================================================
// K3a: slot segment partial sums. 254 blocks = 127 row-groups x 2 slot-halves.
// LDS acc[50*300 + 50 cnt]; race-free: thread d only touches addrs == d (mod 300).
// ============================================================
__global__ __launch_bounds__(320) void slot_seg_partial(
    const float* __restrict__ enc1, const int* __restrict__ sl1,
    float* __restrict__ part) {
  __shared__ float acc[15050];
  int gid = blockIdx.x;
  int g = gid >> 1, h = gid & 1;
  int tid = threadIdx.x;
  for (int i = tid; i < 15050; i += 320) acc[i] = 0.f;
  __syncthreads();
  int base = h * 50;
  for (int rr = 0; rr < 128; rr++) {
    int j = g * 128 + rr;
    int bb = j / 127, tt = j % 127 + 1;
    int l = sl1[bb * TT_ + tt] - base;
    if (l >= 0 && l < 50) {
      if (tid < ED)       acc[l * ED + tid] += enc1[(size_t)(bb * TT_ + tt) * ED + tid];
      else if (tid == ED) acc[15000 + l] += 1.f;
    }
  }
  __syncthreads();
  float* dst = part + (size_t)gid * 15050;
  for (int i = tid; i < 15050; i += 320) dst[i] = acc[i];
}

// K3b: reduce partials across the 127 groups
__global__ void slot_seg_final(const float* __restrict__ part,
                               float* __restrict__ ssum, float* __restrict__ scnt) {
  int idx = blockIdx.x * 256 + threadIdx.x;
  if (idx < 30000) {
    int S = idx / ED, d = idx % ED;
    int h = S / 50, ls = S % 50;
    float a = 0.f;
    for (int g = 0; g < 127; g++) a += part[(size_t)(g * 2 + h) * 15050 + ls * ED + d];
    ssum[idx] = a;
  } else if (idx < 30100) {
    int S = idx - 30000;
    int h = S / 50, ls = S % 50;
    float a = 0.f;
    for (int g = 0; g < 127; g++) a += part[(size_t)(g * 2 + h) * 15050 + 15000 + ls];
    scnt[S] = a;
  }
}

// ============================================================
// K4a: finalize prototypes + counts straight into d_out
// ============================================================
__global__ void finalize_protos(
    const float* __restrict__ ipin, const int* __restrict__ icin,
    const float* __restrict__ spe, const int* __restrict__ scin,
    const float* __restrict__ isum, const float* __restrict__ icnt,
    const float* __restrict__ ssum, const float* __restrict__ scnt,
    float* __restrict__ dout) {
  int idx = blockIdx.x * 256 + threadIdx.x;
  if (idx < 18000) {
    int i = idx / ED;
    float c0 = (float)icin[i];
    dout[O_IPROTO + idx] = (c0 * ipin[idx] + isum[idx]) / (c0 + icnt[i]);
  } else if (idx < 18060) {
    dout[O_ICNT + (idx - 18000)] = (float)ED;
  } else if (idx < 48060) {
    int k = idx - 18060;
    int s = k / ED;
    float c0 = (float)scin[s];
    dout[O_SPROTO + k] = (c0 * spe[k] + ssum[k]) / (c0 + scnt[s]);
  } else if (idx < 48160) {
    int s = idx - 48060;
    dout[O_SCNT + s] = (float)scin[s] + scnt[s];
  }
}

// ============================================================
// K4b: L2-normalize prototypes, store TRANSPOSED into ws
// blocks: 0..59 intent rows, 60..159 slot rows; 320 threads
// ============================================================
__global__ __launch_bounds__(320) void norm_protos(
    const float* __restrict__ dout, float* __restrict__ ws) {
  int row = blockIdx.x;
  const float* src; float* dstT; int nrows; int r;
  if (row < NI) { r = row;      src = dout + O_IPROTO + (size_t)r * ED; dstT = ws + WS_NPTI; nrows = NI; }
  else          { r = row - NI; src = dout + O_SPROTO + (size_t)r * ED; dstT = ws + WS_NPTS; nrows = NS; }
  int tid = threadIdx.x;
  float v = (tid < ED) ? src[tid] : 0.f;
  float ss = v * v;
  #pragma unroll
  for (int o = 32; o > 0; o >>= 1) ss += __shfl_xor(ss, o);
  __shared__ float wsum[5];
  if ((tid & 63) == 0) wsum[tid >> 6] = ss;
  __syncthreads();
  float tot = wsum[0] + wsum[1] + wsum[2] + wsum[3] + wsum[4];
  float den = fmaxf(sqrtf(tot), 1e-8f);
  if (tid < ED) dstT[(size_t)tid * nrows + r] = v / den;
}

// ============================================================
// K5: intent head — one 64-thread wave per batch row
// ============================================================
__global__ __launch_bounds__(64) void intent_head(
    const float* __restrict__ enc2, const float* __restrict__ npTi,
    const int* __restrict__ il2, float* __restrict__ dout,
    float* __restrict__ lossi) {
  int b = blockIdx.x;
  __shared__ float row[ED];
  int tid = threadIdx.x;
  const float* src = enc2 + (size_t)(b * TT_) * ED;
  float ss = 0.f;
  for (int k = tid; k < ED; k += 64) { float v = src[k]; row[k] = v; ss += v * v; }
  #pragma unroll
  for (int o = 32; o > 0; o >>= 1) ss += __shfl_xor(ss, o);
  __syncthreads();
  float den = fmaxf(sqrtf(ss), 1e-8f);
  float dot = 0.f;
  if (tid < NI)
    for (int k = 0; k < ED; k++) dot = fmaf(row[k], npTi[k * NI + tid], dot);
  float sim = dot / den;
  float val = (tid < NI) ? sim : -INFINITY;
  float m = val;
  #pragma unroll
  for (int o = 32; o > 0; o >>= 1) m = fmaxf(m, __shfl_xor(m, o));
  float e = (tid < NI) ? expf(sim - m) : 0.f;
  float s = e;
  #pragma unroll
  for (int o = 32; o > 0; o >>= 1) s += __shfl_xor(s, o);
  float prob = e / s;
  if (tid < NI) dout[O_ILOG + b * NI + tid] = prob;
  float pv = (tid < NI) ? prob : -INFINITY;
  float m2 = pv;
  #pragma unroll
  for (int o = 32; o > 0; o >>= 1) m2 = fmaxf(m2, __shfl_xor(m2, o));
  float e2 = (tid < NI) ? expf(prob - m2) : 0.f;
  float s2 = e2;
  #pragma unroll
  for (int o = 32; o > 0; o >>= 1) s2 += __shfl_xor(s2, o);
  int lbl = il2[b];
  float picked = __shfl(prob, lbl);
  if (tid == 0) lossi[b] = m2 + logf(s2) - picked;
}

// ============================================================
// K6: slot head — 8 token rows per 128-thread block
// ============================================================
__device__ __forceinline__ float bsum128(float v, float* red2) {
  #pragma unroll
  for (int o = 32; o > 0; o >>= 1) v += __shfl_xor(v, o);
  __syncthreads();
  if ((threadIdx.x & 63) == 0) red2[threadIdx.x >> 6] = v;
  __syncthreads();
  return red2[0] + red2[1];
}
__device__ __forceinline__ float bmax128(float v, float* red2) {
  #pragma unroll
  for (int o = 32; o > 0; o >>= 1) v = fmaxf(v, __shfl_xor(v, o));
  __syncthreads();
  if ((threadIdx.x & 63) == 0) red2[threadIdx.x >> 6] = v;
  __syncthreads();
  return fmaxf(red2[0], red2[1]);
}

#define RPB 8
__global__ __launch_bounds__(128) void slot_head(
    const float* __restrict__ enc2, const float* __restrict__ npTs,
    const int* __restrict__ sl2, const float* __restrict__ bO,
    const float* __restrict__ bX, float* __restrict__ dout,
    float* __restrict__ losss) {
  __shared__ float rows[RPB][ED];
  __shared__ float den[RPB];
  __shared__ float red2[2];
  __shared__ float pickedS;
  int tid = threadIdx.x;
  int jb = blockIdx.x * RPB;
  for (int idx = tid; idx < RPB * ED; idx += 128) {
    int r = idx / ED, k = idx % ED;
    int j = jb + r;
    int bb = j / 127, tt = j % 127 + 1;
    rows[r][k] = enc2[(size_t)(bb * TT_ + tt) * ED + k];
  }
  __syncthreads();
  #pragma unroll
  for (int r = 0; r < RPB; r++) {
    float ss = 0.f;
    for (int k = tid; k < ED; k += 128) { float v = rows[r][k]; ss += v * v; }
    ss = bsum128(ss, red2);
    if (tid == 0) den[r] = fmaxf(sqrtf(ss), 1e-8f);
  }
  __syncthreads();
  float acc[RPB] = {};
  int p = tid;
  bool act = p < NS;
  for (int k = 0; k < ED; k += 4) {
    float w0 = act ? npTs[(size_t)(k + 0) * NS + p] : 0.f;
    float w1 = act ? npTs[(size_t)(k + 1) * NS + p] : 0.f;
    float w2 = act ? npTs[(size_t)(k + 2) * NS + p] : 0.f;
    float w3 = act ? npTs[(size_t)(k + 3) * NS + p] : 0.f;
    #pragma unroll
    for (int r = 0; r < RPB; r++) {
      float4 rv = *(const float4*)&rows[r][k];
      acc[r] = fmaf(rv.x, w0, acc[r]);
      acc[r] = fmaf(rv.y, w1, acc[r]);
      acc[r] = fmaf(rv.z, w2, acc[r]);
      acc[r] = fmaf(rv.w, w3, acc[r]);
    }
  }
  float vO = *bO, vX = *bX;
  for (int r = 0; r < RPB; r++) {
    int j = jb + r;
    int bb = j / 127, tt = j % 127 + 1;
    float sim = acc[r] / den[r];
    if (p == 0) sim = vO;
    if (p == 1) sim = vX;
    float val = act ? sim : -INFINITY;
    float m = bmax128(val, red2);
    float e = act ? expf(sim - m) : 0.f;
    float s = bsum128(e, red2);
    float prob = e / s;
    if (act) dout[O_SLOG + (size_t)j * NS + p] = prob;
    float pv = act ? prob : -INFINITY;
    float m2 = bmax128(pv, red2);
    int lbl = sl2[bb * TT_ + tt];
    if (p == lbl) pickedS = prob;
    float e2 = act ? expf(prob - m2) : 0.f;
    float s2 = bsum128(e2, red2);   // syncs inside also order pickedS
    if (tid == 0) losss[j] = m2 + logf(s2) - pickedS;
  }
}

// ============================================================
// K7: final loss reduction
// ============================================================
__global__ __launch_bounds__(256) void loss_final(
    const float* __restrict__ li, const float* __restrict__ lsv,
    float* __restrict__ dout) {
  __shared__ float red[256];
  int tid = threadIdx.x;
  float a = (tid < BB_) ? li[tid] : 0.f;
  red[tid] = a;
  __syncthreads();
  for (int o = 128; o > 0; o >>= 1) {
    if (tid < o) red[tid] += red[tid + o];
    __syncthreads();
  }
  float il = red[0];
  __syncthreads();
  float bsum = 0.f;
  for (int i = tid; i < NTOK; i += 256) bsum += lsv[i];
  red[tid] = bsum;
  __syncthreads();
  for (int o = 128; o > 0; o >>= 1) {
    if (tid < o) red[tid] += red[tid + o];
    __syncthreads();
  }
  if (tid == 0) {
    float ilm = il / 128.f;
    float slm = red[0] / 16256.f;
    dout[O_ILOSS] = ilm;
    dout[O_SLOSS] = slm;
    dout[O_TLOSS] = ilm + slm;
  }
}

// ============================================================
extern "C" void kernel_launch(void* const* d_in, const int* in_sizes, int n_in,
                              void* d_out, int out_size, void* d_ws, size_t ws_size,
                              hipStream_t stream) {
  const float* lm1  = (const float*)d_in[0];
  const float* lm2  = (const float*)d_in[1];
  const int*   il1  = (const int*)d_in[2];
  const int*   il2  = (const int*)d_in[3];
  const int*   sl1  = (const int*)d_in[4];
  const int*   sl2  = (const int*)d_in[5];
  const float* ipin = (const float*)d_in[6];
  const int*   icin = (const int*)d_in[7];
  const float* spin = (const float*)d_in[8];
  const int*   scin = (const int*)d_in[9];
  const float* W    = (const float*)d_in[10];
  const float* benc = (const float*)d_in[11];
  const float* bO   = (const float*)d_in[12];
  const float* bX   = (const float*)d_in[13];
  float* out = (float*)d_out;
  float* ws  = (float*)d_ws;

  gemm_enc<<<514, 320, 0, stream>>>(lm1, lm2, spin, W, benc, ws);
  intent_seg<<<60, 320, 0, stream>>>(ws + WS_ENC1, il1, ws + WS_ISUM, ws + WS_ICNT);
  slot_seg_partial<<<254, 320, 0, stream>>>(ws + WS_ENC1, sl1, ws + WS_PART);
  slot_seg_final<<<118, 256, 0, stream>>>(ws + WS_PART, ws + WS_SSUM, ws + WS_SCNT);
  finalize_protos<<<189, 256, 0, stream>>>(ipin, icin, ws + WS_SPE, scin,
                                           ws + WS_ISUM, ws + WS_ICNT,
                                           ws + WS_SSUM, ws + WS_SCNT, out);
  norm_protos<<<160, 320, 0, stream>>>(out, ws);
  intent_head<<<128, 64, 0, stream>>>(ws + WS_ENC2, ws + WS_NPTI, il2, out, ws + WS_LOSSI);
  slot_head<<<2032, 128, 0, stream>>>(ws + WS_ENC2, ws + WS_NPTS, sl2, bO, bX, out, ws + WS_LOSSS);
  loss_final<<<1, 256, 0, stream>>>(ws + WS_LOSSI, ws + WS_LOSSS, out);
}

// Round 3
// 573.851 us; speedup vs baseline: 1.5831x; 1.5831x over previous
//
#include <hip/hip_runtime.h>
#include <math.h>

// Problem constants
#define BB_ 128      // batch
#define TT_ 128      // seq len
#define HDIM 768
#define ED 300       // ENCODER_DIM
#define NI 60        // NUM_INTENTS
#define NS 100       // NUM_SLOTS
#define NTOK 16256   // B*(T-1)

// ---- workspace layout (float offsets); ~55.2 MB of d_ws ----
#define WS_ENC1  0          // (B*T, 300)
#define WS_ENC2  4915200    // (B*T, 300)
#define WS_SPE   9830400    // (100, 300) slot_proto_enc
#define WS_ISUM  9860400    // (60,300)
#define WS_ICNT  9878400    // (60)
#define WS_NPTI  9878464    // (300,60)  normalized intent protos, transposed
#define WS_NPTS  9896464    // (300,100) normalized slot protos, transposed
#define WS_SSUM  9926464    // (100,300)
#define WS_SCNT  9956464    // (100)
#define WS_PART  9956608    // 254 * 15050 partial slot segment sums (ALSO reused
                            // earlier in the call as W_prep: 960KB split-bf16 W)
#define WS_LOSSI 13779328   // (128)
#define WS_LOSSS 13779456   // (16256)

// ---- output layout (float offsets into d_out) ----
#define O_ILOG   0          // (128,1,60)
#define O_SLOG   7680       // (128,127,1,100)
#define O_ILOSS  1633280
#define O_SLOSS  1633281
#define O_TLOSS  1633282
#define O_IPROTO 1633283    // (60,300)
#define O_ICNT   1651283    // (60)
#define O_SPROTO 1651343    // (100,300)
#define O_SCNT   1681343    // (100)

typedef __attribute__((ext_vector_type(8))) __bf16 bf16x8;
typedef __attribute__((ext_vector_type(4))) float f32x4;

// ---- split-bf16 helpers: x = hi + lo, both RNE bf16 ----
__device__ __forceinline__ unsigned bf16_rne_u(float x) {
  unsigned u = __float_as_uint(x);
  return (u + 0x7FFFu + ((u >> 16) & 1u)) >> 16;
}
__device__ __forceinline__ void split2(float x, float y, unsigned& hi, unsigned& lo) {
  unsigned hx = bf16_rne_u(x), hy = bf16_rne_u(y);
  float rx = x - __uint_as_float(hx << 16);
  float ry = y - __uint_as_float(hy << 16);
  unsigned lx = bf16_rne_u(rx), ly = bf16_rne_u(ry);
  hi = hx | (hy << 16);
  lo = lx | (ly << 16);
}

// ============================================================
// prep_w: split W (300x768 f32) into hi/lo bf16 in MFMA fragment layout.
// Layout (bytes, 24 k-steps): ks*40960 + [hi:0 | lo:20480] + nf*1024 + c*64 + kg*16
//   where n = nf*16+c (0..319, >=300 zero-padded), k = ks*32 + kg*8 + j.
// One thread per 16B slot: 24*20*16*4 = 30720 threads.
// ============================================================
__global__ __launch_bounds__(256) void prep_w(const float* __restrict__ W,
                                              uint4* __restrict__ Wp) {
  int t = blockIdx.x * 256 + threadIdx.x;
  if (t >= 30720) return;
  int ks  = t / 1280;
  int rem = t - ks * 1280;
  int nf  = rem >> 6;
  int c   = (rem >> 2) & 15;
  int kg  = rem & 3;
  int n   = nf * 16 + c;
  int kb  = ks * 32 + kg * 8;
  float4 x0 = make_float4(0.f, 0.f, 0.f, 0.f), x1 = x0;
  if (n < 300) {
    x0 = *(const float4*)(W + (size_t)n * HDIM + kb);
    x1 = *(const float4*)(W + (size_t)n * HDIM + kb + 4);
  }
  unsigned h0, l0, h1, l1, h2, l2, h3, l3;
  split2(x0.x, x0.y, h0, l0); split2(x0.z, x0.w, h1, l1);
  split2(x1.x, x1.y, h2, l2); split2(x1.z, x1.w, h3, l3);
  size_t base = (size_t)ks * 2560;          // uint4 units per ks chunk (40960B)
  int slot = nf * 64 + c * 4 + kg;          // uint4 index in hi region (20KB)
  Wp[base + slot]        = make_uint4(h0, h1, h2, h3);
  Wp[base + 1280 + slot] = make_uint4(l0, l1, l2, l3);
}

// ============================================================
// K1: encoder GEMM via split-bf16 MFMA (3 products: hh + lh + hl).
// C[m,n] = sum_k X[m,k]*W[n,k] + b[n]; M=32868 (lm1|lm2|spin), N=300(pad 320), K=768.
// Block: BM=64 rows, full N. 512 thr = 8 waves; wave w: M-frag (w&3), N-half (w>>2).
// LDS 48KB: Bs[40KB: hi|lo frag layout] As[8KB: hi|lo, r*64+kg*16].
// All LDS frag reads/writes are dense 1KB permutations -> conflict-free.
// Software pipeline: global->reg prefetch of tile ks+1 under compute of ks.
// ============================================================
__global__ __launch_bounds__(512) void gemm_enc_mfma(
    const float* __restrict__ lm1, const float* __restrict__ lm2,
    const float* __restrict__ spin, const uint4* __restrict__ Wp,
    const float* __restrict__ bias, float* __restrict__ ws) {
  __shared__ __align__(16) unsigned char smem[49152];
  int mt = blockIdx.x;
  int m0 = mt * 64;
  const float* src; int srow, mrows;
  if (mt < 256)      { src = lm1;  srow = m0;         mrows = 64; }
  else if (mt < 512) { src = lm2;  srow = m0 - 16384; mrows = 64; }
  else               { src = spin; srow = m0 - 32768; mrows = 100 - srow; }

  int tid = threadIdx.x;
  int l = tid & 63, w = tid >> 6;
  int mf = w & 3, nh = w >> 2;

  // A loader coords: thread -> (row, k-group, half-octet)
  int ar = tid >> 3;          // 0..63
  int akg = (tid >> 1) & 3;   // 0..3
  int ahalf = tid & 1;        // 0..1
  bool aval = ar < mrows;
  const float* aptr = src + (size_t)(srow + ar) * HDIM + akg * 8 + ahalf * 4;
  unsigned aoff_w = 40960 + tid * 8;   // == r*64 + kg*16 + half*8 (+As base)

  // fragment read offsets (dense per-wave)
  int fro = ((l & 15) << 6) + ((l >> 4) << 4);   // c*64 + kg*16
  const unsigned char* aro = smem + 40960 + (mf << 10) + fro;
  const unsigned char* bro = smem + ((nh * 10) << 10) + fro;

  f32x4 acc[10];
  #pragma unroll
  for (int i = 0; i < 10; i++) acc[i] = (f32x4)0.f;

  // prologue: prefetch tile 0 into regs
  float4 areg = aval ? *(const float4*)(aptr) : make_float4(0.f, 0.f, 0.f, 0.f);
  uint4 breg[5];
  {
    const uint4* wp = Wp;
    #pragma unroll
    for (int i = 0; i < 5; i++) breg[i] = wp[i * 512 + tid];
  }

  for (int ks = 0; ks < 24; ks++) {
    // ---- write staged regs to LDS ----
    {
      unsigned h0, l0, h1, l1;
      split2(areg.x, areg.y, h0, l0);
      split2(areg.z, areg.w, h1, l1);
      *(uint2*)(smem + aoff_w)        = make_uint2(h0, h1);
      *(uint2*)(smem + aoff_w + 4096) = make_uint2(l0, l1);
      uint4* bs = (uint4*)smem;
      #pragma unroll
      for (int i = 0; i < 5; i++) bs[i * 512 + tid] = breg[i];
    }
    __syncthreads();
    // ---- prefetch next tile into regs (overlaps compute below) ----
    if (ks < 23) {
      areg = aval ? *(const float4*)(aptr + (ks + 1) * 32)
                  : make_float4(0.f, 0.f, 0.f, 0.f);
      const uint4* wp = Wp + (size_t)(ks + 1) * 2560;
      #pragma unroll
      for (int i = 0; i < 5; i++) breg[i] = wp[i * 512 + tid];
    }
    // ---- compute ----
    bf16x8 ah = *(const bf16x8*)(aro);
    bf16x8 al = *(const bf16x8*)(aro + 4096);
    #pragma unroll
    for (int nf = 0; nf < 10; nf++) {
      bf16x8 bh = *(const bf16x8*)(bro + (nf << 10));
      bf16x8 bl = *(const bf16x8*)(bro + (nf << 10) + 20480);
      acc[nf] = __builtin_amdgcn_mfma_f32_16x16x32_bf16(ah, bh, acc[nf], 0, 0, 0);
      acc[nf] = __builtin_amdgcn_mfma_f32_16x16x32_bf16(al, bh, acc[nf], 0, 0, 0);
      acc[nf] = __builtin_amdgcn_mfma_f32_16x16x32_bf16(ah, bl, acc[nf], 0, 0, 0);
    }
    __syncthreads();
  }

  // ---- epilogue: C row=(l>>4)*4+r (+mf*16), col=l&15 (+nfg*16) ----
  int rbase = (mf << 4) + ((l >> 4) << 2);
  #pragma unroll
  for (int nf = 0; nf < 10; nf++) {
    int n = ((nh * 10 + nf) << 4) + (l & 15);
    if (n >= 300) continue;
    float bn = bias[n];
    #pragma unroll
    for (int r = 0; r < 4; r++) {
      int lr = rbase + r;
      if (lr < mrows) ws[(size_t)(m0 + lr) * ED + n] = acc[nf][r] + bn;
    }
  }
}

// ============================================================
// K2: intent segment sums (deterministic)
// ============================================================
__global__ __launch_bounds__(320) void intent_seg(
    const float* __restrict__ enc1, const int* __restrict__ il1,
    float* __restrict__ isum, float* __restrict__ icnt) {
  int seg = blockIdx.x, tid = threadIdx.x;
  if (tid < ED) {
    float a = 0.f;
    for (int b = 0; b < BB_; b++)
      if (il1[b] == seg) a += enc1[(size_t)(b * TT_) * ED + tid];
    isum[seg * ED + tid] = a;
  } else if (tid == ED) {
    float c = 0.f;
    for (int b = 0; b < BB_; b++) c += (il1[b] == seg) ? 1.f : 0.f;
    icnt[seg] = c;
  }
}

// ============================================================
// K3a: slot segment partial sums (254 blocks = 127 row-groups x 2 slot-halves)
// ============================================================
__global__ __launch_bounds__(320) void slot_seg_partial(
    const float* __restrict__ enc1, const int* __restrict__ sl1,
    float* __restrict__ part) {
  __shared__ float acc[15050];
  int gid = blockIdx.x;
  int g = gid >> 1, h = gid & 1;
  int tid = threadIdx.x;
  for (int i = tid; i < 15050; i += 320) acc[i] = 0.f;
  __syncthreads();
  int base = h * 50;
  for (int rr = 0; rr < 128; rr++) {
    int j = g * 128 + rr;
    int bb = j / 127, tt = j % 127 + 1;
    int l = sl1[bb * TT_ + tt] - base;
    if (l >= 0 && l < 50) {
      if (tid < ED)       acc[l * ED + tid] += enc1[(size_t)(bb * TT_ + tt) * ED + tid];
      else if (tid == ED) acc[15000 + l] += 1.f;
    }
  }
  __syncthreads();
  float* dst = part + (size_t)gid * 15050;
  for (int i = tid; i < 15050; i += 320) dst[i] = acc[i];
}

// K3b: reduce partials across the 127 groups
__global__ void slot_seg_final(const float* __restrict__ part,
                               float* __restrict__ ssum, float* __restrict__ scnt) {
  int idx = blockIdx.x * 256 + threadIdx.x;
  if (idx < 30000) {
    int S = idx / ED, d = idx % ED;
    int h = S / 50, ls = S % 50;
    float a = 0.f;
    for (int g = 0; g < 127; g++) a += part[(size_t)(g * 2 + h) * 15050 + ls * ED + d];
    ssum[idx] = a;
  } else if (idx < 30100) {
    int S = idx - 30000;
    int h = S / 50, ls = S % 50;
    float a = 0.f;
    for (int g = 0; g < 127; g++) a += part[(size_t)(g * 2 + h) * 15050 + 15000 + ls];
    scnt[S] = a;
  }
}

// ============================================================
// K4a: finalize prototypes + counts straight into d_out
// ============================================================
__global__ void finalize_protos(
    const float* __restrict__ ipin, const int* __restrict__ icin,
    const float* __restrict__ spe, const int* __restrict__ scin,
    const float* __restrict__ isum, const float* __restrict__ icnt,
    const float* __restrict__ ssum, const float* __restrict__ scnt,
    float* __restrict__ dout) {
  int idx = blockIdx.x * 256 + threadIdx.x;
  if (idx < 18000) {
    int i = idx / ED;
    float c0 = (float)icin[i];
    dout[O_IPROTO + idx] = (c0 * ipin[idx] + isum[idx]) / (c0 + icnt[i]);
  } else if (idx < 18060) {
    dout[O_ICNT + (idx - 18000)] = (float)ED;
  } else if (idx < 48060) {
    int k = idx - 18060;
    int s = k / ED;
    float c0 = (float)scin[s];
    dout[O_SPROTO + k] = (c0 * spe[k] + ssum[k]) / (c0 + scnt[s]);
  } else if (idx < 48160) {
    int s = idx - 48060;
    dout[O_SCNT + s] = (float)scin[s] + scnt[s];
  }
}

// ============================================================
// K4b: L2-normalize prototypes, store TRANSPOSED into ws
// ============================================================
__global__ __launch_bounds__(320) void norm_protos(
    const float* __restrict__ dout, float* __restrict__ ws) {
  int row = blockIdx.x;
  const float* src; float* dstT; int nrows; int r;
  if (row < NI) { r = row;      src = dout + O_IPROTO + (size_t)r * ED; dstT = ws + WS_NPTI; nrows = NI; }
  else          { r = row - NI; src = dout + O_SPROTO + (size_t)r * ED; dstT = ws + WS_NPTS; nrows = NS; }
  int tid = threadIdx.x;
  float v = (tid < ED) ? src[tid] : 0.f;
  float ss = v * v;
  #pragma unroll
  for (int o = 32; o > 0; o >>= 1) ss += __shfl_xor(ss, o);
  __shared__ float wsum[5];
  if ((tid & 63) == 0) wsum[tid >> 6] = ss;
  __syncthreads();
  float tot = wsum[0] + wsum[1] + wsum[2] + wsum[3] + wsum[4];
  float den = fmaxf(sqrtf(tot), 1e-8f);
  if (tid < ED) dstT[(size_t)tid * nrows + r] = v / den;
}

// ============================================================
// K5: intent head — one 64-thread wave per batch row
// ============================================================
__global__ __launch_bounds__(64) void intent_head(
    const float* __restrict__ enc2, const float* __restrict__ npTi,
    const int* __restrict__ il2, float* __restrict__ dout,
    float* __restrict__ lossi) {
  int b = blockIdx.x;
  __shared__ float row[ED];
  int tid = threadIdx.x;
  const float* src = enc2 + (size_t)(b * TT_) * ED;
  float ss = 0.f;
  for (int k = tid; k < ED; k += 64) { float v = src[k]; row[k] = v; ss += v * v; }
  #pragma unroll
  for (int o = 32; o > 0; o >>= 1) ss += __shfl_xor(ss, o);
  __syncthreads();
  float den = fmaxf(sqrtf(ss), 1e-8f);
  float dot = 0.f;
  if (tid < NI)
    for (int k = 0; k < ED; k++) dot = fmaf(row[k], npTi[k * NI + tid], dot);
  float sim = dot / den;
  float val = (tid < NI) ? sim : -INFINITY;
  float m = val;
  #pragma unroll
  for (int o = 32; o > 0; o >>= 1) m = fmaxf(m, __shfl_xor(m, o));
  float e = (tid < NI) ? expf(sim - m) : 0.f;
  float s = e;
  #pragma unroll
  for (int o = 32; o > 0; o >>= 1) s += __shfl_xor(s, o);
  float prob = e / s;
  if (tid < NI) dout[O_ILOG + b * NI + tid] = prob;
  float pv = (tid < NI) ? prob : -INFINITY;
  float m2 = pv;
  #pragma unroll
  for (int o = 32; o > 0; o >>= 1) m2 = fmaxf(m2, __shfl_xor(m2, o));
  float e2 = (tid < NI) ? expf(prob - m2) : 0.f;
  float s2 = e2;
  #pragma unroll
  for (int o = 32; o > 0; o >>= 1) s2 += __shfl_xor(s2, o);
  int lbl = il2[b];
  float picked = __shfl(prob, lbl);
  if (tid == 0) lossi[b] = m2 + logf(s2) - picked;
}

// ============================================================
// K6: slot head — 8 token rows per 128-thread block
// ============================================================
__device__ __forceinline__ float bsum128(float v, float* red2) {
  #pragma unroll
  for (int o = 32; o > 0; o >>= 1) v += __shfl_xor(v, o);
  __syncthreads();
  if ((threadIdx.x & 63) == 0) red2[threadIdx.x >> 6] = v;
  __syncthreads();
  return red2[0] + red2[1];
}
__device__ __forceinline__ float bmax128(float v, float* red2) {
  #pragma unroll
  for (int o = 32; o > 0; o >>= 1) v = fmaxf(v, __shfl_xor(v, o));
  __syncthreads();
  if ((threadIdx.x & 63) == 0) red2[threadIdx.x >> 6] = v;
  __syncthreads();
  return fmaxf(red2[0], red2[1]);
}

#define RPB 8
__global__ __launch_bounds__(128) void slot_head(
    const float* __restrict__ enc2, const float* __restrict__ npTs,
    const int* __restrict__ sl2, const float* __restrict__ bO,
    const float* __restrict__ bX, float* __restrict__ dout,
    float* __restrict__ losss) {
  __shared__ float rows[RPB][ED];
  __shared__ float den[RPB];
  __shared__ float red2[2];
  __shared__ float pickedS;
  int tid = threadIdx.x;
  int jb = blockIdx.x * RPB;
  for (int idx = tid; idx < RPB * ED; idx += 128) {
    int r = idx / ED, k = idx % ED;
    int j = jb + r;
    int bb = j / 127, tt = j % 127 + 1;
    rows[r][k] = enc2[(size_t)(bb * TT_ + tt) * ED + k];
  }
  __syncthreads();
  #pragma unroll
  for (int r = 0; r < RPB; r++) {
    float ss = 0.f;
    for (int k = tid; k < ED; k += 128) { float v = rows[r][k]; ss += v * v; }
    ss = bsum128(ss, red2);
    if (tid == 0) den[r] = fmaxf(sqrtf(ss), 1e-8f);
  }
  __syncthreads();
  float acc[RPB] = {};
  int p = tid;
  bool act = p < NS;
  for (int k = 0; k < ED; k += 4) {
    float w0 = act ? npTs[(size_t)(k + 0) * NS + p] : 0.f;
    float w1 = act ? npTs[(size_t)(k + 1) * NS + p] : 0.f;
    float w2 = act ? npTs[(size_t)(k + 2) * NS + p] : 0.f;
    float w3 = act ? npTs[(size_t)(k + 3) * NS + p] : 0.f;
    #pragma unroll
    for (int r = 0; r < RPB; r++) {
      float4 rv = *(const float4*)&rows[r][k];
      acc[r] = fmaf(rv.x, w0, acc[r]);
      acc[r] = fmaf(rv.y, w1, acc[r]);
      acc[r] = fmaf(rv.z, w2, acc[r]);
      acc[r] = fmaf(rv.w, w3, acc[r]);
    }
  }
  float vO = *bO, vX = *bX;
  for (int r = 0; r < RPB; r++) {
    int j = jb + r;
    int bb = j / 127, tt = j % 127 + 1;
    float sim = acc[r] / den[r];
    if (p == 0) sim = vO;
    if (p == 1) sim = vX;
    float val = act ? sim : -INFINITY;
    float m = bmax128(val, red2);
    float e = act ? expf(sim - m) : 0.f;
    float s = bsum128(e, red2);
    float prob = e / s;
    if (act) dout[O_SLOG + (size_t)j * NS + p] = prob;
    float pv = act ? prob : -INFINITY;
    float m2 = bmax128(pv, red2);
    int lbl = sl2[bb * TT_ + tt];
    if (p == lbl) pickedS = prob;
    float e2 = act ? expf(prob - m2) : 0.f;
    float s2 = bsum128(e2, red2);   // syncs inside also order pickedS
    if (tid == 0) losss[j] = m2 + logf(s2) - pickedS;
  }
}

// ============================================================
// K7: final loss reduction
// ============================================================
__global__ __launch_bounds__(256) void loss_final(
    const float* __restrict__ li, const float* __restrict__ lsv,
    float* __restrict__ dout) {
  __shared__ float red[256];
  int tid = threadIdx.x;
  float a = (tid < BB_) ? li[tid] : 0.f;
  red[tid] = a;
  __syncthreads();
  for (int o = 128; o > 0; o >>= 1) {
    if (tid < o) red[tid] += red[tid + o];
    __syncthreads();
  }
  float il = red[0];
  __syncthreads();
  float bsum = 0.f;
  for (int i = tid; i < NTOK; i += 256) bsum += lsv[i];
  red[tid] = bsum;
  __syncthreads();
  for (int o = 128; o > 0; o >>= 1) {
    if (tid < o) red[tid] += red[tid + o];
    __syncthreads();
  }
  if (tid == 0) {
    float ilm = il / 128.f;
    float slm = red[0] / 16256.f;
    dout[O_ILOSS] = ilm;
    dout[O_SLOSS] = slm;
    dout[O_TLOSS] = ilm + slm;
  }
}

// ============================================================
extern "C" void kernel_launch(void* const* d_in, const int* in_sizes, int n_in,
                              void* d_out, int out_size, void* d_ws, size_t ws_size,
                              hipStream_t stream) {
  const float* lm1  = (const float*)d_in[0];
  const float* lm2  = (const float*)d_in[1];
  const int*   il1  = (const int*)d_in[2];
  const int*   il2  = (const int*)d_in[3];
  const int*   sl1  = (const int*)d_in[4];
  const int*   sl2  = (const int*)d_in[5];
  const float* ipin = (const float*)d_in[6];
  const int*   icin = (const int*)d_in[7];
  const float* spin = (const float*)d_in[8];
  const int*   scin = (const int*)d_in[9];
  const float* W    = (const float*)d_in[10];
  const float* benc = (const float*)d_in[11];
  const float* bO   = (const float*)d_in[12];
  const float* bX   = (const float*)d_in[13];
  float* out = (float*)d_out;
  float* ws  = (float*)d_ws;
  uint4* Wp  = (uint4*)(ws + WS_PART);   // 960KB, reused later by slot_seg partials

  prep_w<<<120, 256, 0, stream>>>(W, Wp);
  gemm_enc_mfma<<<514, 512, 0, stream>>>(lm1, lm2, spin, Wp, benc, ws);
  intent_seg<<<60, 320, 0, stream>>>(ws + WS_ENC1, il1, ws + WS_ISUM, ws + WS_ICNT);
  slot_seg_partial<<<254, 320, 0, stream>>>(ws + WS_ENC1, sl1, ws + WS_PART);
  slot_seg_final<<<118, 256, 0, stream>>>(ws + WS_PART, ws + WS_SSUM, ws + WS_SCNT);
  finalize_protos<<<189, 256, 0, stream>>>(ipin, icin, ws + WS_SPE, scin,
                                           ws + WS_ISUM, ws + WS_ICNT,
                                           ws + WS_SSUM, ws + WS_SCNT, out);
  norm_protos<<<160, 320, 0, stream>>>(out, ws);
  intent_head<<<128, 64, 0, stream>>>(ws + WS_ENC2, ws + WS_NPTI, il2, out, ws + WS_LOSSI);
  slot_head<<<2032, 128, 0, stream>>>(ws + WS_ENC2, ws + WS_NPTS, sl2, bO, bX, out, ws + WS_LOSSS);
  loss_final<<<1, 256, 0, stream>>>(ws + WS_LOSSI, ws + WS_LOSSS, out);
}

// Round 10
// 369.521 us; speedup vs baseline: 2.4585x; 1.5530x over previous
//
#include <hip/hip_runtime.h>
#include <math.h>

// Problem constants
#define BB_ 128      // batch
#define TT_ 128      // seq len
#define HDIM 768
#define ED 300       // ENCODER_DIM
#define NI 60        // NUM_INTENTS
#define NS 100       // NUM_SLOTS
#define NTOK 16256   // B*(T-1)

// ---- workspace layout (float offsets); ~55.2 MB of d_ws ----
#define WS_ENC1  0          // (B*T, 300)
#define WS_ENC2  4915200    // (B*T, 300)
#define WS_SPE   9830400    // (100, 300) slot_proto_enc
#define WS_ISUM  9860400    // (60,300)
#define WS_ICNT  9878400    // (60)
#define WS_NPTI  9878464    // (300,60)  normalized intent protos, transposed
#define WS_NPTS  9896464    // (300,100) normalized slot protos, transposed
#define WS_SSUM  9926464    // (100,300)
#define WS_SCNT  9956464    // (100)
#define WS_PART  9956608    // 254 * 15050 partial slot segment sums (ALSO reused
                            // earlier in the call as W_prep: 960KB split-bf16 W)
#define WS_LOSSI 13779328   // (128)
#define WS_LOSSS 13779456   // (16256)

// ---- output layout (float offsets into d_out) ----
#define O_ILOG   0          // (128,1,60)
#define O_SLOG   7680       // (128,127,1,100)
#define O_ILOSS  1633280
#define O_SLOSS  1633281
#define O_TLOSS  1633282
#define O_IPROTO 1633283    // (60,300)
#define O_ICNT   1651283    // (60)
#define O_SPROTO 1651343    // (100,300)
#define O_SCNT   1681343    // (100)

typedef __attribute__((ext_vector_type(8))) __bf16 bf16x8;
typedef __attribute__((ext_vector_type(4))) float f32x4;

// ---- split-bf16 helpers: x = hi + lo, both RNE bf16 ----
__device__ __forceinline__ unsigned bf16_rne_u(float x) {
  unsigned u = __float_as_uint(x);
  return (u + 0x7FFFu + ((u >> 16) & 1u)) >> 16;
}
__device__ __forceinline__ void split2(float x, float y, unsigned& hi, unsigned& lo) {
  unsigned hx = bf16_rne_u(x), hy = bf16_rne_u(y);
  float rx = x - __uint_as_float(hx << 16);
  float ry = y - __uint_as_float(hy << 16);
  unsigned lx = bf16_rne_u(rx), ly = bf16_rne_u(ry);
  hi = hx | (hy << 16);
  lo = lx | (ly << 16);
}

// async global->LDS, 16B per lane; LDS dest = wave-uniform base + lane*16
__device__ __forceinline__ void gl_lds16(const uint4* g, void* l) {
  __builtin_amdgcn_global_load_lds(
      (const __attribute__((address_space(1))) void*)g,
      (__attribute__((address_space(3))) void*)l, 16, 0, 0);
}

// ============================================================
// prep_w: split W (300x768 f32) into hi/lo bf16, fragment layout chosen so
// LDS fragment reads are lane-contiguous after a LINEAR global_load_lds copy.
// uint4 index: ks*2560 + [hi:0 | lo:+1280] + nf*64 + kg*16 + c
//   n = nf*16 + c (>=300 zero-padded), k = ks*32 + kg*8 + j.
// ============================================================
__global__ __launch_bounds__(256) void prep_w(const float* __restrict__ W,
                                              uint4* __restrict__ Wp) {
  int t = blockIdx.x * 256 + threadIdx.x;
  if (t >= 30720) return;
  int ks  = t / 1280;
  int rem = t - ks * 1280;
  int nf  = rem >> 6;
  int c   = (rem >> 2) & 15;
  int kg  = rem & 3;
  int n   = nf * 16 + c;
  int kb  = ks * 32 + kg * 8;
  float4 x0 = make_float4(0.f, 0.f, 0.f, 0.f), x1 = x0;
  if (n < 300) {
    x0 = *(const float4*)(W + (size_t)n * HDIM + kb);
    x1 = *(const float4*)(W + (size_t)n * HDIM + kb + 4);
  }
  unsigned h0, l0, h1, l1, h2, l2, h3, l3;
  split2(x0.x, x0.y, h0, l0); split2(x0.z, x0.w, h1, l1);
  split2(x1.x, x1.y, h2, l2); split2(x1.z, x1.w, h3, l3);
  size_t base = (size_t)ks * 2560;
  int slot = nf * 64 + kg * 16 + c;       // lane-contiguous read layout
  Wp[base + slot]        = make_uint4(h0, h1, h2, h3);
  Wp[base + 1280 + slot] = make_uint4(l0, l1, l2, l3);
}

// ============================================================
// K1: encoder GEMM via split-bf16 MFMA (3 products: hh + lh + hl).
// M=32868 (lm1|lm2|spin), N=300(pad 320), K=768. BM=64, full N per block.
// 512 thr = 8 waves; wave w: M-frag (w&3), N-half (w>>2); acc f32x4[10].
// B staged via global_load_lds (zero VGPR), A via 4-VGPR prefetch pipeline.
// LDS 48KB single buffer:
//   B [0,40960): hi nf*1024 + kg*256 + c*16 ; lo +20480   (read = lane*16)
//   A [40960,49152): hi mf*1024 + kg*256 + r16*16 ; lo +4096 (read = lane*16)
// ============================================================
__global__ __launch_bounds__(512, 4) void gemm_enc_mfma(
    const float* __restrict__ lm1, const float* __restrict__ lm2,
    const float* __restrict__ spin, const uint4* __restrict__ Wp,
    const float* __restrict__ bias, float* __restrict__ ws) {
  __shared__ __align__(16) unsigned char smem[49152];
  int mt = blockIdx.x, m0 = mt * 64;
  const float* src; int srow, mrows;
  if (mt < 256)      { src = lm1;  srow = m0;         mrows = 64; }
  else if (mt < 512) { src = lm2;  srow = m0 - 16384; mrows = 64; }
  else               { src = spin; srow = m0 - 32768; mrows = 100 - srow; }

  int tid = threadIdx.x;
  int l = tid & 63, w = tid >> 6;
  int mf = w & 3, nh = w >> 2;

  // A loader: row = tid>>3 (0..63), a8 = tid&7 (16B unit within 128B k-chunk)
  int ar = tid >> 3, a8 = tid & 7;
  bool aval = ar < mrows;
  const float* aptr = src + (size_t)(srow + ar) * HDIM + a8 * 4;
  // A LDS write: grp=ar>>4, kg=a8>>1, r16=ar&15, half=a8&1 (8B granule)
  unsigned aw = 40960u + ((unsigned)(ar >> 4) << 10) + ((unsigned)(a8 >> 1) << 8)
              + ((unsigned)(ar & 15) << 4) + ((unsigned)(a8 & 1) << 3);

  // lane-contiguous fragment read bases
  const unsigned char* arop = smem + 40960 + (mf << 10) + l * 16;
  const unsigned char* brop = smem + ((nh * 10) << 10) + l * 16;

  f32x4 acc[10];
  #pragma unroll
  for (int i = 0; i < 10; i++) acc[i] = (f32x4)0.f;

  float4 areg = aval ? *(const float4*)(aptr) : make_float4(0.f, 0.f, 0.f, 0.f);

  for (int ks = 0; ks < 24; ks++) {
    // A: split staged regs, write to LDS
    {
      unsigned h0, l0, h1, l1;
      split2(areg.x, areg.y, h0, l0);
      split2(areg.z, areg.w, h1, l1);
      *(uint2*)(smem + aw)        = make_uint2(h0, h1);
      *(uint2*)(smem + aw + 4096) = make_uint2(l0, l1);
    }
    // B: async stage 40KB (8 waves x 5 x 1KB chunks), linear global->LDS
    {
      const uint4* gp = Wp + (size_t)ks * 2560 + (size_t)(w * 5) * 64 + l;
      #pragma unroll
      for (int i = 0; i < 5; i++)
        gl_lds16(gp + i * 64, smem + (w * 5 + i) * 1024);
    }
    __syncthreads();   // drains ds_write + global_load_lds
    // prefetch next A tile (HBM latency hides under compute)
    if (ks < 23)
      areg = aval ? *(const float4*)(aptr + (ks + 1) * 32)
                  : make_float4(0.f, 0.f, 0.f, 0.f);
    bf16x8 ah = *(const bf16x8*)(arop);
    bf16x8 al = *(const bf16x8*)(arop + 4096);
    #pragma unroll
    for (int nf = 0; nf < 10; nf++) {
      bf16x8 bh = *(const bf16x8*)(brop + (nf << 10));
      bf16x8 bl = *(const bf16x8*)(brop + (nf << 10) + 20480);
      acc[nf] = __builtin_amdgcn_mfma_f32_16x16x32_bf16(ah, bh, acc[nf], 0, 0, 0);
      acc[nf] = __builtin_amdgcn_mfma_f32_16x16x32_bf16(al, bh, acc[nf], 0, 0, 0);
      acc[nf] = __builtin_amdgcn_mfma_f32_16x16x32_bf16(ah, bl, acc[nf], 0, 0, 0);
    }
    __syncthreads();
  }

  // epilogue: D row = mf*16 + (l>>4)*4 + r, col = (nh*10+nf)*16 + (l&15)
  int rbase = (mf << 4) + ((l >> 4) << 2);
  #pragma unroll
  for (int nf = 0; nf < 10; nf++) {
    int n = ((nh * 10 + nf) << 4) + (l & 15);
    if (n >= 300) continue;
    float bn = bias[n];
    #pragma unroll
    for (int r = 0; r < 4; r++) {
      int lr = rbase + r;
      if (lr < mrows) ws[(size_t)(m0 + lr) * ED + n] = acc[nf][r] + bn;
    }
  }
}

// ============================================================
// K2: intent segment sums (deterministic)
// ============================================================
__global__ __launch_bounds__(320) void intent_seg(
    const float* __restrict__ enc1, const int* __restrict__ il1,
    float* __restrict__ isum, float* __restrict__ icnt) {
  int seg = blockIdx.x, tid = threadIdx.x;
  if (tid < ED) {
    float a = 0.f;
    for (int b = 0; b < BB_; b++)
      if (il1[b] == seg) a += enc1[(size_t)(b * TT_) * ED + tid];
    isum[seg * ED + tid] = a;
  } else if (tid == ED) {
    float c = 0.f;
    for (int b = 0; b < BB_; b++) c += (il1[b] == seg) ? 1.f : 0.f;
    icnt[seg] = c;
  }
}

// ============================================================
// K3a: slot segment partial sums (254 blocks = 127 row-groups x 2 slot-halves)
// ============================================================
__global__ __launch_bounds__(320) void slot_seg_partial(
    const float* __restrict__ enc1, const int* __restrict__ sl1,
    float* __restrict__ part) {
  __shared__ float acc[15050];
  int gid = blockIdx.x;
  int g = gid >> 1, h = gid & 1;
  int tid = threadIdx.x;
  for (int i = tid; i < 15050; i += 320) acc[i] = 0.f;
  __syncthreads();
  int base = h * 50;
  for (int rr = 0; rr < 128; rr++) {
    int j = g * 128 + rr;
    int bb = j / 127, tt = j % 127 + 1;
    int l = sl1[bb * TT_ + tt] - base;
    if (l >= 0 && l < 50) {
      if (tid < ED)       acc[l * ED + tid] += enc1[(size_t)(bb * TT_ + tt) * ED + tid];
      else if (tid == ED) acc[15000 + l] += 1.f;
    }
  }
  __syncthreads();
  float* dst = part + (size_t)gid * 15050;
  for (int i = tid; i < 15050; i += 320) dst[i] = acc[i];
}

// K3b: reduce partials across the 127 groups
__global__ void slot_seg_final(const float* __restrict__ part,
                               float* __restrict__ ssum, float* __restrict__ scnt) {
  int idx = blockIdx.x * 256 + threadIdx.x;
  if (idx < 30000) {
    int S = idx / ED, d = idx % ED;
    int h = S / 50, ls = S % 50;
    float a = 0.f;
    for (int g = 0; g < 127; g++) a += part[(size_t)(g * 2 + h) * 15050 + ls * ED + d];
    ssum[idx] = a;
  } else if (idx < 30100) {
    int S = idx - 30000;
    int h = S / 50, ls = S % 50;
    float a = 0.f;
    for (int g = 0; g < 127; g++) a += part[(size_t)(g * 2 + h) * 15050 + 15000 + ls];
    scnt[S] = a;
  }
}

// ============================================================
// K4a: finalize prototypes + counts straight into d_out
// ============================================================
__global__ void finalize_protos(
    const float* __restrict__ ipin, const int* __restrict__ icin,
    const float* __restrict__ spe, const int* __restrict__ scin,
    const float* __restrict__ isum, const float* __restrict__ icnt,
    const float* __restrict__ ssum, const float* __restrict__ scnt,
    float* __restrict__ dout) {
  int idx = blockIdx.x * 256 + threadIdx.x;
  if (idx < 18000) {
    int i = idx / ED;
    float c0 = (float)icin[i];
    dout[O_IPROTO + idx] = (c0 * ipin[idx] + isum[idx]) / (c0 + icnt[i]);
  } else if (idx < 18060) {
    dout[O_ICNT + (idx - 18000)] = (float)ED;
  } else if (idx < 48060) {
    int k = idx - 18060;
    int s = k / ED;
    float c0 = (float)scin[s];
    dout[O_SPROTO + k] = (c0 * spe[k] + ssum[k]) / (c0 + scnt[s]);
  } else if (idx < 48160) {
    int s = idx - 48060;
    dout[O_SCNT + s] = (float)scin[s] + scnt[s];
  }
}

// ============================================================
// K4b: L2-normalize prototypes, store TRANSPOSED into ws
// ============================================================
__global__ __launch_bounds__(320) void norm_protos(
    const float* __restrict__ dout, float* __restrict__ ws) {
  int row = blockIdx.x;
  const float* src; float* dstT; int nrows; int r;
  if (row < NI) { r = row;      src = dout + O_IPROTO + (size_t)r * ED; dstT = ws + WS_NPTI; nrows = NI; }
  else          { r = row - NI; src = dout + O_SPROTO + (size_t)r * ED; dstT = ws + WS_NPTS; nrows = NS; }
  int tid = threadIdx.x;
  float v = (tid < ED) ? src[tid] : 0.f;
  float ss = v * v;
  #pragma unroll
  for (int o = 32; o > 0; o >>= 1) ss += __shfl_xor(ss, o);
  __shared__ float wsum[5];
  if ((tid & 63) == 0) wsum[tid >> 6] = ss;
  __syncthreads();
  float tot = wsum[0] + wsum[1] + wsum[2] + wsum[3] + wsum[4];
  float den = fmaxf(sqrtf(tot), 1e-8f);
  if (tid < ED) dstT[(size_t)tid * nrows + r] = v / den;
}

// ============================================================
// K5: intent head — one 64-thread wave per batch row
// ============================================================
__global__ __launch_bounds__(64) void intent_head(
    const float* __restrict__ enc2, const float* __restrict__ npTi,
    const int* __restrict__ il2, float* __restrict__ dout,
    float* __restrict__ lossi) {
  int b = blockIdx.x;
  __shared__ float row[ED];
  int tid = threadIdx.x;
  const float* src = enc2 + (size_t)(b * TT_) * ED;
  float ss = 0.f;
  for (int k = tid; k < ED; k += 64) { float v = src[k]; row[k] = v; ss += v * v; }
  #pragma unroll
  for (int o = 32; o > 0; o >>= 1) ss += __shfl_xor(ss, o);
  __syncthreads();
  float den = fmaxf(sqrtf(ss), 1e-8f);
  float dot = 0.f;
  if (tid < NI)
    for (int k = 0; k < ED; k++) dot = fmaf(row[k], npTi[k * NI + tid], dot);
  float sim = dot / den;
  float val = (tid < NI) ? sim : -INFINITY;
  float m = val;
  #pragma unroll
  for (int o = 32; o > 0; o >>= 1) m = fmaxf(m, __shfl_xor(m, o));
  float e = (tid < NI) ? expf(sim - m) : 0.f;
  float s = e;
  #pragma unroll
  for (int o = 32; o > 0; o >>= 1) s += __shfl_xor(s, o);
  float prob = e / s;
  if (tid < NI) dout[O_ILOG + b * NI + tid] = prob;
  float pv = (tid < NI) ? prob : -INFINITY;
  float m2 = pv;
  #pragma unroll
  for (int o = 32; o > 0; o >>= 1) m2 = fmaxf(m2, __shfl_xor(m2, o));
  float e2 = (tid < NI) ? expf(prob - m2) : 0.f;
  float s2 = e2;
  #pragma unroll
  for (int o = 32; o > 0; o >>= 1) s2 += __shfl_xor(s2, o);
  int lbl = il2[b];
  float picked = __shfl(prob, lbl);
  if (tid == 0) lossi[b] = m2 + logf(s2) - picked;
}

// ============================================================
// K6: slot head — 8 token rows per 128-thread block
// ============================================================
__device__ __forceinline__ float bsum128(float v, float* red2) {
  #pragma unroll
  for (int o = 32; o > 0; o >>= 1) v += __shfl_xor(v, o);
  __syncthreads();
  if ((threadIdx.x & 63) == 0) red2[threadIdx.x >> 6] = v;
  __syncthreads();
  return red2[0] + red2[1];
}
__device__ __forceinline__ float bmax128(float v, float* red2) {
  #pragma unroll
  for (int o = 32; o > 0; o >>= 1) v = fmaxf(v, __shfl_xor(v, o));
  __syncthreads();
  if ((threadIdx.x & 63) == 0) red2[threadIdx.x >> 6] = v;
  __syncthreads();
  return fmaxf(red2[0], red2[1]);
}

#define RPB 8
__global__ __launch_bounds__(128) void slot_head(
    const float* __restrict__ enc2, const float* __restrict__ npTs,
    const int* __restrict__ sl2, const float* __restrict__ bO,
    const float* __restrict__ bX, float* __restrict__ dout,
    float* __restrict__ losss) {
  __shared__ float rows[RPB][ED];
  __shared__ float den[RPB];
  __shared__ float red2[2];
  __shared__ float pickedS;
  int tid = threadIdx.x;
  int jb = blockIdx.x * RPB;
  for (int idx = tid; idx < RPB * ED; idx += 128) {
    int r = idx / ED, k = idx % ED;
    int j = jb + r;
    int bb = j / 127, tt = j % 127 + 1;
    rows[r][k] = enc2[(size_t)(bb * TT_ + tt) * ED + k];
  }
  __syncthreads();
  #pragma unroll
  for (int r = 0; r < RPB; r++) {
    float ss = 0.f;
    for (int k = tid; k < ED; k += 128) { float v = rows[r][k]; ss += v * v; }
    ss = bsum128(ss, red2);
    if (tid == 0) den[r] = fmaxf(sqrtf(ss), 1e-8f);
  }
  __syncthreads();
  float acc[RPB] = {};
  int p = tid;
  bool act = p < NS;
  for (int k = 0; k < ED; k += 4) {
    float w0 = act ? npTs[(size_t)(k + 0) * NS + p] : 0.f;
    float w1 = act ? npTs[(size_t)(k + 1) * NS + p] : 0.f;
    float w2 = act ? npTs[(size_t)(k + 2) * NS + p] : 0.f;
    float w3 = act ? npTs[(size_t)(k + 3) * NS + p] : 0.f;
    #pragma unroll
    for (int r = 0; r < RPB; r++) {
      float4 rv = *(const float4*)&rows[r][k];
      acc[r] = fmaf(rv.x, w0, acc[r]);
      acc[r] = fmaf(rv.y, w1, acc[r]);
      acc[r] = fmaf(rv.z, w2, acc[r]);
      acc[r] = fmaf(rv.w, w3, acc[r]);
    }
  }
  float vO = *bO, vX = *bX;
  for (int r = 0; r < RPB; r++) {
    int j = jb + r;
    int bb = j / 127, tt = j % 127 + 1;
    float sim = acc[r] / den[r];
    if (p == 0) sim = vO;
    if (p == 1) sim = vX;
    float val = act ? sim : -INFINITY;
    float m = bmax128(val, red2);
    float e = act ? expf(sim - m) : 0.f;
    float s = bsum128(e, red2);
    float prob = e / s;
    if (act) dout[O_SLOG + (size_t)j * NS + p] = prob;
    float pv = act ? prob : -INFINITY;
    float m2 = bmax128(pv, red2);
    int lbl = sl2[bb * TT_ + tt];
    if (p == lbl) pickedS = prob;
    float e2 = act ? expf(prob - m2) : 0.f;
    float s2 = bsum128(e2, red2);   // syncs inside also order pickedS
    if (tid == 0) losss[j] = m2 + logf(s2) - pickedS;
  }
}

// ============================================================
// K7: final loss reduction
// ============================================================
__global__ __launch_bounds__(256) void loss_final(
    const float* __restrict__ li, const float* __restrict__ lsv,
    float* __restrict__ dout) {
  __shared__ float red[256];
  int tid = threadIdx.x;
  float a = (tid < BB_) ? li[tid] : 0.f;
  red[tid] = a;
  __syncthreads();
  for (int o = 128; o > 0; o >>= 1) {
    if (tid < o) red[tid] += red[tid + o];
    __syncthreads();
  }
  float il = red[0];
  __syncthreads();
  float bsum = 0.f;
  for (int i = tid; i < NTOK; i += 256) bsum += lsv[i];
  red[tid] = bsum;
  __syncthreads();
  for (int o = 128; o > 0; o >>= 1) {
    if (tid < o) red[tid] += red[tid + o];
    __syncthreads();
  }
  if (tid == 0) {
    float ilm = il / 128.f;
    float slm = red[0] / 16256.f;
    dout[O_ILOSS] = ilm;
    dout[O_SLOSS] = slm;
    dout[O_TLOSS] = ilm + slm;
  }
}

// ============================================================
extern "C" void kernel_launch(void* const* d_in, const int* in_sizes, int n_in,
                              void* d_out, int out_size, void* d_ws, size_t ws_size,
                              hipStream_t stream) {
  const float* lm1  = (const float*)d_in[0];
  const float* lm2  = (const float*)d_in[1];
  const int*   il1  = (const int*)d_in[2];
  const int*   il2  = (const int*)d_in[3];
  const int*   sl1  = (const int*)d_in[4];
  const int*   sl2  = (const int*)d_in[5];
  const float* ipin = (const float*)d_in[6];
  const int*   icin = (const int*)d_in[7];
  const float* spin = (const float*)d_in[8];
  const int*   scin = (const int*)d_in[9];
  const float* W    = (const float*)d_in[10];
  const float* benc = (const float*)d_in[11];
  const float* bO   = (const float*)d_in[12];
  const float* bX   = (const float*)d_in[13];
  float* out = (float*)d_out;
  float* ws  = (float*)d_ws;
  uint4* Wp  = (uint4*)(ws + WS_PART);   // 960KB, reused later by slot_seg partials

  prep_w<<<120, 256, 0, stream>>>(W, Wp);
  gemm_enc_mfma<<<514, 512, 0, stream>>>(lm1, lm2, spin, Wp, benc, ws);
  intent_seg<<<60, 320, 0, stream>>>(ws + WS_ENC1, il1, ws + WS_ISUM, ws + WS_ICNT);
  slot_seg_partial<<<254, 320, 0, stream>>>(ws + WS_ENC1, sl1, ws + WS_PART);
  slot_seg_final<<<118, 256, 0, stream>>>(ws + WS_PART, ws + WS_SSUM, ws + WS_SCNT);
  finalize_protos<<<189, 256, 0, stream>>>(ipin, icin, ws + WS_SPE, scin,
                                           ws + WS_ISUM, ws + WS_ICNT,
                                           ws + WS_SSUM, ws + WS_SCNT, out);
  norm_protos<<<160, 320, 0, stream>>>(out, ws);
  intent_head<<<128, 64, 0, stream>>>(ws + WS_ENC2, ws + WS_NPTI, il2, out, ws + WS_LOSSI);
  slot_head<<<2032, 128, 0, stream>>>(ws + WS_ENC2, ws + WS_NPTS, sl2, bO, bX, out, ws + WS_LOSSS);
  loss_final<<<1, 256, 0, stream>>>(ws + WS_LOSSI, ws + WS_LOSSS, out);
}

// Round 12
// 335.312 us; speedup vs baseline: 2.7094x; 1.1020x over previous
//
#include <hip/hip_runtime.h>
#include <math.h>

// Problem constants
#define BB_ 128      // batch
#define TT_ 128      // seq len
#define HDIM 768
#define ED 300       // ENCODER_DIM
#define NI 60        // NUM_INTENTS
#define NS 100       // NUM_SLOTS
#define NTOK 16256   // B*(T-1)

// ---- workspace layout (float offsets); ~55.2 MB of d_ws ----
#define WS_ENC1  0          // (B*T, 300)
#define WS_ENC2  4915200    // (B*T, 300)
#define WS_SPE   9830400    // (100, 300) slot_proto_enc
#define WS_ISUM  9860400    // (60,300)
#define WS_ICNT  9878400    // (60)
#define WS_NPTI  9878464    // (300,60)  normalized intent protos, transposed
#define WS_NPTS  9896464    // (300,100) normalized slot protos, transposed
#define WS_SSUM  9926464    // (100,300)
#define WS_SCNT  9956464    // (100)
#define WS_PART  9956608    // 254*15050 slot partials; ALSO reused as W_prep (960KB)
                            // before, and as npTs-frag buffer (140KB) after
#define WS_LOSSI 13779328   // (128)
#define WS_LOSSS 13779456   // (16256)

// ---- output layout (float offsets into d_out) ----
#define O_ILOG   0          // (128,1,60)
#define O_SLOG   7680       // (128,127,1,100)
#define O_ILOSS  1633280
#define O_SLOSS  1633281
#define O_TLOSS  1633282
#define O_IPROTO 1633283    // (60,300)
#define O_ICNT   1651283    // (60)
#define O_SPROTO 1651343    // (100,300)
#define O_SCNT   1681343    // (100)

typedef __attribute__((ext_vector_type(8))) __bf16 bf16x8;
typedef __attribute__((ext_vector_type(4))) float f32x4;

// ---- split-bf16 helpers: x = hi + lo, both RNE bf16 ----
__device__ __forceinline__ unsigned bf16_rne_u(float x) {
  unsigned u = __float_as_uint(x);
  return (u + 0x7FFFu + ((u >> 16) & 1u)) >> 16;
}
__device__ __forceinline__ void split2(float x, float y, unsigned& hi, unsigned& lo) {
  unsigned hx = bf16_rne_u(x), hy = bf16_rne_u(y);
  float rx = x - __uint_as_float(hx << 16);
  float ry = y - __uint_as_float(hy << 16);
  unsigned lx = bf16_rne_u(rx), ly = bf16_rne_u(ry);
  hi = hx | (hy << 16);
  lo = lx | (ly << 16);
}

// async global->LDS, 16B per lane; LDS dest = wave-uniform base + lane*16
__device__ __forceinline__ void gl_lds16(const uint4* g, void* l) {
  __builtin_amdgcn_global_load_lds(
      (const __attribute__((address_space(1))) void*)g,
      (__attribute__((address_space(3))) void*)l, 16, 0, 0);
}

// ============================================================
// prep_w: split W (300x768 f32) into hi/lo bf16, fragment layout chosen so
// LDS fragment reads are lane-contiguous after a LINEAR global_load_lds copy.
// uint4 index: ks*2560 + [hi:0 | lo:+1280] + nf*64 + kg*16 + c
// ============================================================
__global__ __launch_bounds__(256) void prep_w(const float* __restrict__ W,
                                              uint4* __restrict__ Wp) {
  int t = blockIdx.x * 256 + threadIdx.x;
  if (t >= 30720) return;
  int ks  = t / 1280;
  int rem = t - ks * 1280;
  int nf  = rem >> 6;
  int c   = (rem >> 2) & 15;
  int kg  = rem & 3;
  int n   = nf * 16 + c;
  int kb  = ks * 32 + kg * 8;
  float4 x0 = make_float4(0.f, 0.f, 0.f, 0.f), x1 = x0;
  if (n < 300) {
    x0 = *(const float4*)(W + (size_t)n * HDIM + kb);
    x1 = *(const float4*)(W + (size_t)n * HDIM + kb + 4);
  }
  unsigned h0, l0, h1, l1, h2, l2, h3, l3;
  split2(x0.x, x0.y, h0, l0); split2(x0.z, x0.w, h1, l1);
  split2(x1.x, x1.y, h2, l2); split2(x1.z, x1.w, h3, l3);
  size_t base = (size_t)ks * 2560;
  int slot = nf * 64 + kg * 16 + c;
  Wp[base + slot]        = make_uint4(h0, h1, h2, h3);
  Wp[base + 1280 + slot] = make_uint4(l0, l1, l2, l3);
}

// ============================================================
// K1: encoder GEMM via split-bf16 MFMA (unchanged from measured round-10).
// ============================================================
__global__ __launch_bounds__(512, 4) void gemm_enc_mfma(
    const float* __restrict__ lm1, const float* __restrict__ lm2,
    const float* __restrict__ spin, const uint4* __restrict__ Wp,
    const float* __restrict__ bias, float* __restrict__ ws) {
  __shared__ __align__(16) unsigned char smem[49152];
  int mt = blockIdx.x, m0 = mt * 64;
  const float* src; int srow, mrows;
  if (mt < 256)      { src = lm1;  srow = m0;         mrows = 64; }
  else if (mt < 512) { src = lm2;  srow = m0 - 16384; mrows = 64; }
  else               { src = spin; srow = m0 - 32768; mrows = 100 - srow; }

  int tid = threadIdx.x;
  int l = tid & 63, w = tid >> 6;
  int mf = w & 3, nh = w >> 2;

  int ar = tid >> 3, a8 = tid & 7;
  bool aval = ar < mrows;
  const float* aptr = src + (size_t)(srow + ar) * HDIM + a8 * 4;
  unsigned aw = 40960u + ((unsigned)(ar >> 4) << 10) + ((unsigned)(a8 >> 1) << 8)
              + ((unsigned)(ar & 15) << 4) + ((unsigned)(a8 & 1) << 3);

  const unsigned char* arop = smem + 40960 + (mf << 10) + l * 16;
  const unsigned char* brop = smem + ((nh * 10) << 10) + l * 16;

  f32x4 acc[10];
  #pragma unroll
  for (int i = 0; i < 10; i++) acc[i] = (f32x4)0.f;

  float4 areg = aval ? *(const float4*)(aptr) : make_float4(0.f, 0.f, 0.f, 0.f);

  for (int ks = 0; ks < 24; ks++) {
    {
      unsigned h0, l0, h1, l1;
      split2(areg.x, areg.y, h0, l0);
      split2(areg.z, areg.w, h1, l1);
      *(uint2*)(smem + aw)        = make_uint2(h0, h1);
      *(uint2*)(smem + aw + 4096) = make_uint2(l0, l1);
    }
    {
      const uint4* gp = Wp + (size_t)ks * 2560 + (size_t)(w * 5) * 64 + l;
      #pragma unroll
      for (int i = 0; i < 5; i++)
        gl_lds16(gp + i * 64, smem + (w * 5 + i) * 1024);
    }
    __syncthreads();
    if (ks < 23)
      areg = aval ? *(const float4*)(aptr + (ks + 1) * 32)
                  : make_float4(0.f, 0.f, 0.f, 0.f);
    bf16x8 ah = *(const bf16x8*)(arop);
    bf16x8 al = *(const bf16x8*)(arop + 4096);
    #pragma unroll
    for (int nf = 0; nf < 10; nf++) {
      bf16x8 bh = *(const bf16x8*)(brop + (nf << 10));
      bf16x8 bl = *(const bf16x8*)(brop + (nf << 10) + 20480);
      acc[nf] = __builtin_amdgcn_mfma_f32_16x16x32_bf16(ah, bh, acc[nf], 0, 0, 0);
      acc[nf] = __builtin_amdgcn_mfma_f32_16x16x32_bf16(al, bh, acc[nf], 0, 0, 0);
      acc[nf] = __builtin_amdgcn_mfma_f32_16x16x32_bf16(ah, bl, acc[nf], 0, 0, 0);
    }
    __syncthreads();
  }

  int rbase = (mf << 4) + ((l >> 4) << 2);
  #pragma unroll
  for (int nf = 0; nf < 10; nf++) {
    int n = ((nh * 10 + nf) << 4) + (l & 15);
    if (n >= 300) continue;
    float bn = bias[n];
    #pragma unroll
    for (int r = 0; r < 4; r++) {
      int lr = rbase + r;
      if (lr < mrows) ws[(size_t)(m0 + lr) * ED + n] = acc[nf][r] + bn;
    }
  }
}

// ============================================================
// K2: intent segment sums (deterministic)
// ============================================================
__global__ __launch_bounds__(320) void intent_seg(
    const float* __restrict__ enc1, const int* __restrict__ il1,
    float* __restrict__ isum, float* __restrict__ icnt) {
  int seg = blockIdx.x, tid = threadIdx.x;
  if (tid < ED) {
    float a = 0.f;
    for (int b = 0; b < BB_; b++)
      if (il1[b] == seg) a += enc1[(size_t)(b * TT_) * ED + tid];
    isum[seg * ED + tid] = a;
  } else if (tid == ED) {
    float c = 0.f;
    for (int b = 0; b < BB_; b++) c += (il1[b] == seg) ? 1.f : 0.f;
    icnt[seg] = c;
  }
}

// ============================================================
// K3a: slot segment partial sums (254 blocks = 127 row-groups x 2 slot-halves)
// ============================================================
__global__ __launch_bounds__(320) void slot_seg_partial(
    const float* __restrict__ enc1, const int* __restrict__ sl1,
    float* __restrict__ part) {
  __shared__ float acc[15050];
  int gid = blockIdx.x;
  int g = gid >> 1, h = gid & 1;
  int tid = threadIdx.x;
  for (int i = tid; i < 15050; i += 320) acc[i] = 0.f;
  __syncthreads();
  int base = h * 50;
  for (int rr = 0; rr < 128; rr++) {
    int j = g * 128 + rr;
    int bb = j / 127, tt = j % 127 + 1;
    int l = sl1[bb * TT_ + tt] - base;
    if (l >= 0 && l < 50) {
      if (tid < ED)       acc[l * ED + tid] += enc1[(size_t)(bb * TT_ + tt) * ED + tid];
      else if (tid == ED) acc[15000 + l] += 1.f;
    }
  }
  __syncthreads();
  float* dst = part + (size_t)gid * 15050;
  for (int i = tid; i < 15050; i += 320) dst[i] = acc[i];
}

// K3b: reduce partials across the 127 groups
__global__ void slot_seg_final(const float* __restrict__ part,
                               float* __restrict__ ssum, float* __restrict__ scnt) {
  int idx = blockIdx.x * 256 + threadIdx.x;
  if (idx < 30000) {
    int S = idx / ED, d = idx % ED;
    int h = S / 50, ls = S % 50;
    float a = 0.f;
    for (int g = 0; g < 127; g++) a += part[(size_t)(g * 2 + h) * 15050 + ls * ED + d];
    ssum[idx] = a;
  } else if (idx < 30100) {
    int S = idx - 30000;
    int h = S / 50, ls = S % 50;
    float a = 0.f;
    for (int g = 0; g < 127; g++) a += part[(size_t)(g * 2 + h) * 15050 + 15000 + ls];
    scnt[S] = a;
  }
}

// ============================================================
// K4a: finalize prototypes + counts straight into d_out
// ============================================================
__global__ void finalize_protos(
    const float* __restrict__ ipin, const int* __restrict__ icin,
    const float* __restrict__ spe, const int* __restrict__ scin,
    const float* __restrict__ isum, const float* __restrict__ icnt,
    const float* __restrict__ ssum, const float* __restrict__ scnt,
    float* __restrict__ dout) {
  int idx = blockIdx.x * 256 + threadIdx.x;
  if (idx < 18000) {
    int i = idx / ED;
    float c0 = (float)icin[i];
    dout[O_IPROTO + idx] = (c0 * ipin[idx] + isum[idx]) / (c0 + icnt[i]);
  } else if (idx < 18060) {
    dout[O_ICNT + (idx - 18000)] = (float)ED;
  } else if (idx < 48060) {
    int k = idx - 18060;
    int s = k / ED;
    float c0 = (float)scin[s];
    dout[O_SPROTO + k] = (c0 * spe[k] + ssum[k]) / (c0 + scnt[s]);
  } else if (idx < 48160) {
    int s = idx - 48060;
    dout[O_SCNT + s] = (float)scin[s] + scnt[s];
  }
}

// ============================================================
// K4b: L2-normalize prototypes, store TRANSPOSED into ws
// ============================================================
__global__ __launch_bounds__(320) void norm_protos(
    const float* __restrict__ dout, float* __restrict__ ws) {
  int row = blockIdx.x;
  const float* src; float* dstT; int nrows; int r;
  if (row < NI) { r = row;      src = dout + O_IPROTO + (size_t)r * ED; dstT = ws + WS_NPTI; nrows = NI; }
  else          { r = row - NI; src = dout + O_SPROTO + (size_t)r * ED; dstT = ws + WS_NPTS; nrows = NS; }
  int tid = threadIdx.x;
  float v = (tid < ED) ? src[tid] : 0.f;
  float ss = v * v;
  #pragma unroll
  for (int o = 32; o > 0; o >>= 1) ss += __shfl_xor(ss, o);
  __shared__ float wsum[5];
  if ((tid & 63) == 0) wsum[tid >> 6] = ss;
  __syncthreads();
  float tot = wsum[0] + wsum[1] + wsum[2] + wsum[3] + wsum[4];
  float den = fmaxf(sqrtf(tot), 1e-8f);
  if (tid < ED) dstT[(size_t)tid * nrows + r] = v / den;
}

// ============================================================
// prep_npts: split normalized slot protos npTs (300,100 f32, k-major) into
// hi/lo bf16 MFMA fragment layout. N=112 (7 nf), K=320 (10 ks).
// uint4 index: ks*896 + [hi:0 | lo:+448] + nf*64 + kg*16 + c
//   s = nf*16+c (>=100 zero), k = ks*32 + kg*8 + i (>=300 zero).
// ============================================================
__global__ __launch_bounds__(256) void prep_npts(const float* __restrict__ npTs,
                                                 uint4* __restrict__ Wq) {
  int t = blockIdx.x * 256 + threadIdx.x;
  if (t >= 4480) return;
  int ks  = t / 448;
  int rem = t - ks * 448;
  int nf  = rem >> 6;
  int c   = (rem >> 2) & 15;
  int kg  = rem & 3;
  int s   = nf * 16 + c;
  int kb  = ks * 32 + kg * 8;
  float v[8];
  #pragma unroll
  for (int i = 0; i < 8; i++)
    v[i] = (s < NS && (kb + i) < ED) ? npTs[(size_t)(kb + i) * NS + s] : 0.f;
  unsigned h0, l0, h1, l1, h2, l2, h3, l3;
  split2(v[0], v[1], h0, l0); split2(v[2], v[3], h1, l1);
  split2(v[4], v[5], h2, l2); split2(v[6], v[7], h3, l3);
  size_t base = (size_t)ks * 896;
  int slot = nf * 64 + kg * 16 + c;
  Wq[base + slot]       = make_uint4(h0, h1, h2, h3);
  Wq[base + 448 + slot] = make_uint4(l0, l1, l2, l3);
}

// ============================================================
// K5: intent head — one 64-thread wave per batch row (unchanged)
// ============================================================
__global__ __launch_bounds__(64) void intent_head(
    const float* __restrict__ enc2, const float* __restrict__ npTi,
    const int* __restrict__ il2, float* __restrict__ dout,
    float* __restrict__ lossi) {
  int b = blockIdx.x;
  __shared__ float row[ED];
  int tid = threadIdx.x;
  const float* src = enc2 + (size_t)(b * TT_) * ED;
  float ss = 0.f;
  for (int k = tid; k < ED; k += 64) { float v = src[k]; row[k] = v; ss += v * v; }
  #pragma unroll
  for (int o = 32; o > 0; o >>= 1) ss += __shfl_xor(ss, o);
  __syncthreads();
  float den = fmaxf(sqrtf(ss), 1e-8f);
  float dot = 0.f;
  if (tid < NI)
    for (int k = 0; k < ED; k++) dot = fmaf(row[k], npTi[k * NI + tid], dot);
  float sim = dot / den;
  float val = (tid < NI) ? sim : -INFINITY;
  float m = val;
  #pragma unroll
  for (int o = 32; o > 0; o >>= 1) m = fmaxf(m, __shfl_xor(m, o));
  float e = (tid < NI) ? expf(sim - m) : 0.f;
  float s = e;
  #pragma unroll
  for (int o = 32; o > 0; o >>= 1) s += __shfl_xor(s, o);
  float prob = e / s;
  if (tid < NI) dout[O_ILOG + b * NI + tid] = prob;
  float pv = (tid < NI) ? prob : -INFINITY;
  float m2 = pv;
  #pragma unroll
  for (int o = 32; o > 0; o >>= 1) m2 = fmaxf(m2, __shfl_xor(m2, o));
  float e2 = (tid < NI) ? expf(prob - m2) : 0.f;
  float s2 = e2;
  #pragma unroll
  for (int o = 32; o > 0; o >>= 1) s2 += __shfl_xor(s2, o);
  int lbl = il2[b];
  float picked = __shfl(prob, lbl);
  if (tid == 0) lossi[b] = m2 + logf(s2) - picked;
}

// ============================================================
// K6: slot head via split-bf16 MFMA + in-register softmax/CE.
// sims(16256x100) = l2norm(toks2)(16256x300) @ npTs^T. 508 blocks x 128 thr
// (2 waves), 32 rows/block. K=320 in 10 steps. Norm f32 pre-pass.
// LDS: B hi [0,7168) B lo [7168,14336) A hi [14336,16384) A lo [16384,18432)
//      inv_den [18432,18560). Frag reads lane-contiguous (lane*16).
// C layout (proven in gemm): row = mf*16+(l>>4)*4+r, col = nf*16+(l&15).
// Softmax/CE: 16-lane shfl_xor reduces; picked prob via masked sum-reduce.
// ============================================================
__global__ __launch_bounds__(128) void slot_head_mfma(
    const float* __restrict__ enc2, const uint4* __restrict__ Wq,
    const int* __restrict__ sl2, const float* __restrict__ bO,
    const float* __restrict__ bX, float* __restrict__ dout,
    float* __restrict__ losss) {
  __shared__ __align__(16) unsigned char smem[18560];
  float* invd = (float*)(smem + 18432);
  int tid = threadIdx.x;
  int l = tid & 63, w = tid >> 6;       // w = mf (0..1)
  int blk = blockIdx.x;
  int j0 = blk * 32;

  // ---- norm pre-pass: thread t handles (row = t>>2, quarter = t&3) ----
  int nrow = tid >> 2, nq = tid & 3;
  int jn = j0 + nrow;
  int tokn = (jn / 127) * TT_ + (jn % 127) + 1;
  const float* nsrc = enc2 + (size_t)tokn * ED + nq * 75;
  float ss = 0.f;
  for (int i = 0; i < 75; i++) { float v = nsrc[i]; ss = fmaf(v, v, ss); }
  ss += __shfl_xor(ss, 1);
  ss += __shfl_xor(ss, 2);
  if (nq == 0) invd[nrow] = 1.f / fmaxf(sqrtf(ss), 1e-8f);
  __syncthreads();

  // ---- A loader coords (same mapping as norm pass): row=t>>2, kg=t&3 ----
  const float* asrc = enc2 + (size_t)tokn * ED;   // + k0 later
  unsigned awr = 14336u + ((unsigned)(nrow >> 4) << 10) + ((unsigned)nq << 8)
               + ((unsigned)(nrow & 15) << 4);
  float ainv = invd[nrow];

  // fragment read bases
  const unsigned char* arop = smem + 14336 + (w << 10) + l * 16;
  const unsigned char* brop = smem + l * 16;

  f32x4 acc[7];
  #pragma unroll
  for (int i = 0; i < 7; i++) acc[i] = (f32x4)0.f;

  for (int ks = 0; ks < 10; ks++) {
    // A: load 8 floats (guarded vs K=300), scale, split, write frag row
    {
      int k0 = ks * 32 + nq * 8;
      float4 v0 = (k0 <= 296) ? *(const float4*)(asrc + k0)
                              : make_float4(0.f, 0.f, 0.f, 0.f);
      float4 v1 = (k0 + 4 <= 296) ? *(const float4*)(asrc + k0 + 4)
                                  : make_float4(0.f, 0.f, 0.f, 0.f);
      v0.x *= ainv; v0.y *= ainv; v0.z *= ainv; v0.w *= ainv;
      v1.x *= ainv; v1.y *= ainv; v1.z *= ainv; v1.w *= ainv;
      unsigned h0, l0, h1, l1, h2, l2, h3, l3;
      split2(v0.x, v0.y, h0, l0); split2(v0.z, v0.w, h1, l1);
      split2(v1.x, v1.y, h2, l2); split2(v1.z, v1.w, h3, l3);
      *(uint4*)(smem + awr)        = make_uint4(h0, h1, h2, h3);
      *(uint4*)(smem + awr + 2048) = make_uint4(l0, l1, l2, l3);
    }
    // B: 14 x 1KB chunks via global_load_lds, linear
    {
      const uint4* gp = Wq + (size_t)ks * 896;
      #pragma unroll
      for (int i = 0; i < 7; i++) {
        int c1 = i * 2 + w;
        gl_lds16(gp + c1 * 64 + l, smem + c1 * 1024);
      }
    }
    __syncthreads();
    bf16x8 ah = *(const bf16x8*)(arop);
    bf16x8 al = *(const bf16x8*)(arop + 2048);
    #pragma unroll
    for (int nf = 0; nf < 7; nf++) {
      bf16x8 bh = *(const bf16x8*)(brop + (nf << 10));
      bf16x8 bl = *(const bf16x8*)(brop + (nf << 10) + 7168);
      acc[nf] = __builtin_amdgcn_mfma_f32_16x16x32_bf16(ah, bh, acc[nf], 0, 0, 0);
      acc[nf] = __builtin_amdgcn_mfma_f32_16x16x32_bf16(al, bh, acc[nf], 0, 0, 0);
      acc[nf] = __builtin_amdgcn_mfma_f32_16x16x32_bf16(ah, bl, acc[nf], 0, 0, 0);
    }
    __syncthreads();
  }

  // ---- epilogue: softmax + probs store + CE per row ----
  float vO = *bO, vX = *bX;
  int c16 = l & 15, g = l >> 4;
  #pragma unroll
  for (int r = 0; r < 4; r++) {
    int j = j0 + w * 16 + g * 4 + r;
    int tok = (j / 127) * TT_ + (j % 127) + 1;
    int lbl = sl2[tok];
    float sim[7];
    #pragma unroll
    for (int nf = 0; nf < 7; nf++) sim[nf] = acc[nf][r];
    if (c16 == 0) sim[0] = vO;
    if (c16 == 1) sim[0] = vX;
    // max over valid cols
    float mx = -INFINITY;
    #pragma unroll
    for (int nf = 0; nf < 7; nf++) {
      bool valid = (nf < 6) || (c16 < 4);
      float v = valid ? sim[nf] : -INFINITY;
      mx = fmaxf(mx, v);
    }
    mx = fmaxf(mx, __shfl_xor(mx, 1));
    mx = fmaxf(mx, __shfl_xor(mx, 2));
    mx = fmaxf(mx, __shfl_xor(mx, 4));
    mx = fmaxf(mx, __shfl_xor(mx, 8));
    float e[7], s = 0.f;
    #pragma unroll
    for (int nf = 0; nf < 7; nf++) {
      bool valid = (nf < 6) || (c16 < 4);
      e[nf] = valid ? expf(sim[nf] - mx) : 0.f;
      s += e[nf];
    }
    s += __shfl_xor(s, 1);
    s += __shfl_xor(s, 2);
    s += __shfl_xor(s, 4);
    s += __shfl_xor(s, 8);
    float p[7];
    #pragma unroll
    for (int nf = 0; nf < 7; nf++) p[nf] = e[nf] / s;
    #pragma unroll
    for (int nf = 0; nf < 7; nf++) {
      int col = nf * 16 + c16;
      if (col < NS) dout[O_SLOG + (size_t)j * NS + col] = p[nf];
    }
    // CE on probs: logsumexp(probs) - probs[lbl]
    float m2 = -INFINITY;
    #pragma unroll
    for (int nf = 0; nf < 7; nf++) {
      bool valid = (nf < 6) || (c16 < 4);
      m2 = fmaxf(m2, valid ? p[nf] : -INFINITY);
    }
    m2 = fmaxf(m2, __shfl_xor(m2, 1));
    m2 = fmaxf(m2, __shfl_xor(m2, 2));
    m2 = fmaxf(m2, __shfl_xor(m2, 4));
    m2 = fmaxf(m2, __shfl_xor(m2, 8));
    float s2 = 0.f, pick = 0.f;
    #pragma unroll
    for (int nf = 0; nf < 7; nf++) {
      bool valid = (nf < 6) || (c16 < 4);
      if (valid) {
        s2 += expf(p[nf] - m2);
        int col = nf * 16 + c16;
        pick += (col == lbl) ? p[nf] : 0.f;
      }
    }
    s2 += __shfl_xor(s2, 1);
    s2 += __shfl_xor(s2, 2);
    s2 += __shfl_xor(s2, 4);
    s2 += __shfl_xor(s2, 8);
    pick += __shfl_xor(pick, 1);
    pick += __shfl_xor(pick, 2);
    pick += __shfl_xor(pick, 4);
    pick += __shfl_xor(pick, 8);
    if (c16 == 0) losss[j] = m2 + logf(s2) - pick;
  }
}

// ============================================================
// K7: final loss reduction
// ============================================================
__global__ __launch_bounds__(256) void loss_final(
    const float* __restrict__ li, const float* __restrict__ lsv,
    float* __restrict__ dout) {
  __shared__ float red[256];
  int tid = threadIdx.x;
  float a = (tid < BB_) ? li[tid] : 0.f;
  red[tid] = a;
  __syncthreads();
  for (int o = 128; o > 0; o >>= 1) {
    if (tid < o) red[tid] += red[tid + o];
    __syncthreads();
  }
  float il = red[0];
  __syncthreads();
  float bsum = 0.f;
  for (int i = tid; i < NTOK; i += 256) bsum += lsv[i];
  red[tid] = bsum;
  __syncthreads();
  for (int o = 128; o > 0; o >>= 1) {
    if (tid < o) red[tid] += red[tid + o];
    __syncthreads();
  }
  if (tid == 0) {
    float ilm = il / 128.f;
    float slm = red[0] / 16256.f;
    dout[O_ILOSS] = ilm;
    dout[O_SLOSS] = slm;
    dout[O_TLOSS] = ilm + slm;
  }
}

// ============================================================
extern "C" void kernel_launch(void* const* d_in, const int* in_sizes, int n_in,
                              void* d_out, int out_size, void* d_ws, size_t ws_size,
                              hipStream_t stream) {
  const float* lm1  = (const float*)d_in[0];
  const float* lm2  = (const float*)d_in[1];
  const int*   il1  = (const int*)d_in[2];
  const int*   il2  = (const int*)d_in[3];
  const int*   sl1  = (const int*)d_in[4];
  const int*   sl2  = (const int*)d_in[5];
  const float* ipin = (const float*)d_in[6];
  const int*   icin = (const int*)d_in[7];
  const float* spin = (const float*)d_in[8];
  const int*   scin = (const int*)d_in[9];
  const float* W    = (const float*)d_in[10];
  const float* benc = (const float*)d_in[11];
  const float* bO   = (const float*)d_in[12];
  const float* bX   = (const float*)d_in[13];
  float* out = (float*)d_out;
  float* ws  = (float*)d_ws;
  // WS_PART region reuse timeline: Wp (gemm B) -> slot partials -> Wq (npTs frags)
  uint4* Wp  = (uint4*)(ws + WS_PART);
  uint4* Wq  = (uint4*)(ws + WS_PART);

  prep_w<<<120, 256, 0, stream>>>(W, Wp);
  gemm_enc_mfma<<<514, 512, 0, stream>>>(lm1, lm2, spin, Wp, benc, ws);
  intent_seg<<<60, 320, 0, stream>>>(ws + WS_ENC1, il1, ws + WS_ISUM, ws + WS_ICNT);
  slot_seg_partial<<<254, 320, 0, stream>>>(ws + WS_ENC1, sl1, ws + WS_PART);
  slot_seg_final<<<118, 256, 0, stream>>>(ws + WS_PART, ws + WS_SSUM, ws + WS_SCNT);
  finalize_protos<<<189, 256, 0, stream>>>(ipin, icin, ws + WS_SPE, scin,
                                           ws + WS_ISUM, ws + WS_ICNT,
                                           ws + WS_SSUM, ws + WS_SCNT, out);
  norm_protos<<<160, 320, 0, stream>>>(out, ws);
  intent_head<<<128, 64, 0, stream>>>(ws + WS_ENC2, ws + WS_NPTI, il2, out, ws + WS_LOSSI);
  prep_npts<<<18, 256, 0, stream>>>(ws + WS_NPTS, Wq);
  slot_head_mfma<<<508, 128, 0, stream>>>(ws + WS_ENC2, Wq, sl2, bO, bX, out, ws + WS_LOSSS);
  loss_final<<<1, 256, 0, stream>>>(ws + WS_LOSSI, ws + WS_LOSSS, out);
}